// Round 7
// baseline (513.661 us; speedup 1.0000x reference)
//
#include <hip/hip_runtime.h>
#include <hip/hip_bf16.h>

#define IN_F   4096
#define OUT_F  4096
#define HID    64
#define D_LAT  16
#define BLK    16
#define NB     (IN_F * OUT_F / BLK)   // 1,048,576
#define NCODES 65536                   // codebook size
#define M_TOT  8192                    // 4 * 2048
#define K_TOT  IN_F
#define N_TOT  OUT_F
#define NT     (K_TOT / 64)            // 64 K-tiles of BK=64

typedef __bf16 bf16x8 __attribute__((ext_vector_type(8)));
typedef float  f32x4  __attribute__((ext_vector_type(4)));
typedef float  f32x16 __attribute__((ext_vector_type(16)));

#define S_BARRIER()  asm volatile("s_barrier" ::: "memory")
#define WAIT_VM(n)   asm volatile("s_waitcnt vmcnt(" #n ")" ::: "memory")

// ---------------------------------------------------------------- convert x
__global__ __launch_bounds__(256) void convert_x_kernel(
    const float* __restrict__ x, __hip_bfloat16* __restrict__ xb) {
  size_t i = ((size_t)blockIdx.x * 256 + threadIdx.x) * 8;
  const float4* p = (const float4*)(x + i);
  float4 a = p[0], b = p[1];
  union { __hip_bfloat16 h[8]; uint4 q; } u;
  u.h[0] = __float2bfloat16(a.x); u.h[1] = __float2bfloat16(a.y);
  u.h[2] = __float2bfloat16(a.z); u.h[3] = __float2bfloat16(a.w);
  u.h[4] = __float2bfloat16(b.x); u.h[5] = __float2bfloat16(b.y);
  u.h[6] = __float2bfloat16(b.z); u.h[7] = __float2bfloat16(b.w);
  *(uint4*)(xb + i) = u.q;
}

// ---------------------------------------------------------------- decode TABLE (MFMA)
// Decode the 65,536 UNIQUE codebook entries once:
// table[k][16] = relu(codebook[k]@W1 + b1)@W2 + b2   (fp32, no scale/shift).
__global__ __launch_bounds__(256) void decode_table_kernel(
    const float* __restrict__ codebook,
    const float* __restrict__ W1, const float* __restrict__ b1,
    const float* __restrict__ W2, const float* __restrict__ b2,
    float* __restrict__ table) {
  __shared__ __align__(16) __hip_bfloat16 sH[4][16 * 72];  // per-wave h tile
  const int lane = threadIdx.x & 63;
  const int wave = threadIdx.x >> 6;
  const int n = lane & 15;   // col within 16
  const int q = lane >> 4;   // quad
  const bool act = q < 2;    // quads holding real K (k<16) for layer 1

  union { __hip_bfloat16 h[8]; bf16x8 v; } uz;
#pragma unroll
  for (int j = 0; j < 8; j++) uz.h[j] = __float2bfloat16(0.f);
  const bf16x8 zf = uz.v;
  const f32x4 z4 = (f32x4){0.f, 0.f, 0.f, 0.f};

  bf16x8 frag1[4];
#pragma unroll
  for (int g = 0; g < 4; g++) {
    union { __hip_bfloat16 h[8]; bf16x8 v; } u;
#pragma unroll
    for (int j = 0; j < 8; j++) {
      int k = (q * 8 + j) & 15;
      float w = act ? W1[k * HID + g * 16 + n] : 0.f;
      u.h[j] = __float2bfloat16(w);
    }
    frag1[g] = u.v;
  }
  bf16x8 frag2[2];
#pragma unroll
  for (int kk = 0; kk < 2; kk++) {
    union { __hip_bfloat16 h[8]; bf16x8 v; } u;
#pragma unroll
    for (int j = 0; j < 8; j++)
      u.h[j] = __float2bfloat16(W2[(kk * 32 + q * 8 + j) * BLK + n]);
    frag2[kk] = u.v;
  }
  float b1v[4];
#pragma unroll
  for (int g = 0; g < 4; g++) b1v[g] = b1[g * 16 + n];
  const float b2v = b2[n];

  const int c0w = blockIdx.x * 256 + wave * 64;
#pragma unroll 1
  for (int i = 0; i < 4; i++) {
    const int cbase = c0w + i * 16;
    const int id = cbase + n;  // sequential: decoding the codebook itself
    const float4* cp = (const float4*)(codebook + (size_t)id * D_LAT + (q & 1) * 8);
    float4 ca = cp[0], cb = cp[1];
    union { __hip_bfloat16 h[8]; bf16x8 v; } ua;
    ua.h[0] = __float2bfloat16(ca.x); ua.h[1] = __float2bfloat16(ca.y);
    ua.h[2] = __float2bfloat16(ca.z); ua.h[3] = __float2bfloat16(ca.w);
    ua.h[4] = __float2bfloat16(cb.x); ua.h[5] = __float2bfloat16(cb.y);
    ua.h[6] = __float2bfloat16(cb.z); ua.h[7] = __float2bfloat16(cb.w);
    bf16x8 afrag = act ? ua.v : zf;

    f32x4 hC[4];
#pragma unroll
    for (int g = 0; g < 4; g++)
      hC[g] = __builtin_amdgcn_mfma_f32_16x16x32_bf16(afrag, frag1[g], z4, 0, 0, 0);

    __syncthreads();
#pragma unroll
    for (int g = 0; g < 4; g++)
#pragma unroll
      for (int r = 0; r < 4; r++) {
        float hv = fmaxf(hC[g][r] + b1v[g], 0.f);
        sH[wave][(q * 4 + r) * 72 + g * 16 + n] = __float2bfloat16(hv);
      }
    __syncthreads();

    bf16x8 a2_0 = *(const bf16x8*)&sH[wave][n * 72 + q * 8];
    bf16x8 a2_1 = *(const bf16x8*)&sH[wave][n * 72 + 32 + q * 8];
    f32x4 o4 = __builtin_amdgcn_mfma_f32_16x16x32_bf16(a2_0, frag2[0], z4, 0, 0, 0);
    o4 = __builtin_amdgcn_mfma_f32_16x16x32_bf16(a2_1, frag2[1], o4, 0, 0, 0);

#pragma unroll
    for (int r = 0; r < 4; r++) {
      int code = cbase + q * 4 + r;
      table[(size_t)code * BLK + n] = o4[r] + b2v;  // fp32, pre-scale
    }
  }
}

// ---------------------------------------------------------------- gather + de-standardize
__global__ __launch_bounds__(256) void gather_scale_kernel(
    const int* __restrict__ yidx, const float* __restrict__ table,
    const float* __restrict__ scale, const float* __restrict__ shift,
    __hip_bfloat16* __restrict__ What) {
  const int b = blockIdx.x * 256 + threadIdx.x;   // weight-block index
  const int o = blockIdx.x;                        // = b >> 8 (256 blocks/row)
  const float sc = scale[o], sh = shift[o];
  const int id = yidx[b];
  const float4* t = (const float4*)(table + (size_t)id * BLK);
  float4 v0 = t[0], v1 = t[1], v2 = t[2], v3 = t[3];
  union { __hip_bfloat16 h[16]; uint4 q[2]; } u;
  u.h[0]  = __float2bfloat16(v0.x * sc + sh);
  u.h[1]  = __float2bfloat16(v0.y * sc + sh);
  u.h[2]  = __float2bfloat16(v0.z * sc + sh);
  u.h[3]  = __float2bfloat16(v0.w * sc + sh);
  u.h[4]  = __float2bfloat16(v1.x * sc + sh);
  u.h[5]  = __float2bfloat16(v1.y * sc + sh);
  u.h[6]  = __float2bfloat16(v1.z * sc + sh);
  u.h[7]  = __float2bfloat16(v1.w * sc + sh);
  u.h[8]  = __float2bfloat16(v2.x * sc + sh);
  u.h[9]  = __float2bfloat16(v2.y * sc + sh);
  u.h[10] = __float2bfloat16(v2.z * sc + sh);
  u.h[11] = __float2bfloat16(v2.w * sc + sh);
  u.h[12] = __float2bfloat16(v3.x * sc + sh);
  u.h[13] = __float2bfloat16(v3.y * sc + sh);
  u.h[14] = __float2bfloat16(v3.z * sc + sh);
  u.h[15] = __float2bfloat16(v3.w * sc + sh);
  uint4* dst = (uint4*)(What + (size_t)b * BLK);
  dst[0] = u.q[0];
  dst[1] = u.q[1];
}

// ---------------------------------------------------------------- GEMM (1-barrier, 32x32 MFMA)
// Same verified R5 schedule (phases, STAGE macros, swizzle, vmcnt ledger all
// byte-identical); only the LDS->reg reads, MFMA shape (32x32x16, half the
// instructions, ~15% faster matrix pipe) and epilogue mapping change.
// Wave tile 128x64 = 4x2 subtiles of 32x32; acc = 8x f32x16.
// Per phase (mh,nh): 2 m-subtiles x K-chain of 4 (kk=0..3).
// A-frag: row = mh*128 + wm*64 + mt*32 + (lane&31), k = kk*16+(lane>>5)*8+j.
// B-frag: col = nh*128 + wn*32 + (lane&31), same k.
// C/D: col = lane&31, row = (reg&3) + 8*(reg>>2) + 4*(lane>>5)  [m74/m101].
// Bank balance: 8 lanes per 16B slot uniformly over 8 slots (same as the
// measured-0-conflict R5 pattern; bank depends only on physical col byte).
__device__ inline void gload_lds16(const void* g, void* l) {
  __builtin_amdgcn_global_load_lds(
      (const __attribute__((address_space(1))) void*)g,
      (__attribute__((address_space(3))) void*)l, 16, 0, 0);
}

__global__ __launch_bounds__(512, 2) void gemm_32_kernel(
    const __hip_bfloat16* __restrict__ A, const __hip_bfloat16* __restrict__ B,
    const float* __restrict__ bias, float* __restrict__ C) {
  // buf P at P*65536; A half h at +h*16384; B half h at +32768 + h*16384
  __shared__ __align__(16) char ldsb[131072];
  const int tid  = threadIdx.x;
  const int lane = tid & 63;
  const int wave = tid >> 6;
  const int wm = wave >> 2;   // 0..1
  const int wn = wave & 3;    // 0..3

  // XCD-aware swizzle: 512 wgs, 8 XCDs, 64 contiguous wgs per XCD (bijective).
  const int bid = blockIdx.x;
  const int wg  = (bid & 7) * 64 + (bid >> 3);
  const int m0 = (wg >> 4) * 256;   // 32 m-blocks
  const int n0 = (wg & 15) * 256;   // 16 n-blocks

  const __hip_bfloat16* Ab = A + (size_t)m0 * K_TOT;
  const __hip_bfloat16* Bb = B + (size_t)n0 * K_TOT;

  // staging thread geometry (unchanged from R5): load l covers rows
  // l*64..l*64+63 of the half; global source inverse-swizzled so linear LDS
  // dest + swizzled read match.
  const int r0s = tid >> 3;                 // row 0..63   (l=0)
  const int r1s = r0s + 64;                 // row 64..127 (l=1)
  const int cbs = ((tid & 7) << 4) ^ ((r0s & 7) << 4);  // inverse-swizzled col byte
  const size_t e0 = (size_t)r0s * K_TOT + (cbs >> 1);
  const size_t e1 = (size_t)r1s * K_TOT + (cbs >> 1);

  // read-side lane constants (32x32 fragments)
  const int sw = (lane & 7) << 4;
  int cB[4];
#pragma unroll
  for (int kk = 0; kk < 4; kk++) cB[kk] = (kk * 32 + (lane >> 5) * 16) ^ sw;
  const int aRow = (wm * 64 + (lane & 31)) * 128;           // byte base in A half
  const int bRow = 32768 + (wn * 32 + (lane & 31)) * 128;   // byte base in B half

#define STAGE_A(tt, hh, PP) do {                                               \
    gload_lds16(Ab + (size_t)(hh) * 128 * K_TOT + (size_t)(tt) * 64 + e0,      \
                ldsb + (PP) * 65536 + (hh) * 16384 + wave * 1024);             \
    gload_lds16(Ab + (size_t)(hh) * 128 * K_TOT + (size_t)(tt) * 64 + e1,      \
                ldsb + (PP) * 65536 + (hh) * 16384 + 8192 + wave * 1024);      \
  } while (0)
#define STAGE_B(tt, hh, PP) do {                                               \
    gload_lds16(Bb + (size_t)(hh) * 128 * K_TOT + (size_t)(tt) * 64 + e0,      \
                ldsb + (PP) * 65536 + 32768 + (hh) * 16384 + wave * 1024);     \
    gload_lds16(Bb + (size_t)(hh) * 128 * K_TOT + (size_t)(tt) * 64 + e1,      \
                ldsb + (PP) * 65536 + 32768 + (hh) * 16384 + 8192 + wave * 1024);\
  } while (0)

  bf16x8 aF[2][4], bF0[4], bF1[4];
  f32x16 acc[4][2];  // [mh*2+mt][nh]
#pragma unroll
  for (int i = 0; i < 4; i++)
#pragma unroll
    for (int j = 0; j < 2; j++)
#pragma unroll
      for (int e = 0; e < 16; e++) acc[i][j][e] = 0.f;

#define READ_A(PP, mh) do { _Pragma("unroll")                                  \
    for (int mt = 0; mt < 2; ++mt) { _Pragma("unroll")                         \
      for (int kk = 0; kk < 4; ++kk)                                           \
        aF[mt][kk] = *(const bf16x8*)(ldsb + (PP) * 65536 + (mh) * 16384 +     \
                                      aRow + mt * 4096 + cB[kk]);              \
    } } while (0)
#define READ_B(PP, nh, DST) do { _Pragma("unroll")                             \
    for (int kk = 0; kk < 4; ++kk)                                             \
      DST[kk] = *(const bf16x8*)(ldsb + (PP) * 65536 + (nh) * 16384 +          \
                                 bRow + cB[kk]);                               \
  } while (0)
#define MFMA8(mh, nh, BF) do {                                                 \
    __builtin_amdgcn_s_setprio(1);                                             \
    _Pragma("unroll") for (int mt = 0; mt < 2; ++mt) {                         \
      f32x16 c = acc[(mh) * 2 + mt][(nh)];                                     \
      _Pragma("unroll") for (int kk = 0; kk < 4; ++kk)                         \
        c = __builtin_amdgcn_mfma_f32_32x32x16_bf16(aF[mt][kk], BF[kk], c,     \
                                                    0, 0, 0);                  \
      acc[(mh) * 2 + mt][(nh)] = c;                                            \
    }                                                                          \
    __builtin_amdgcn_s_setprio(0);                                             \
  } while (0)

  // prologue: tile0 (4 halves -> buf0: 8 loads), tile1 A0,A1,B0 -> buf1 (6).
  // vmcnt(6) drains tile0; barrier; pre-read A0,B0 of tile0 for P1's MFMA.
  STAGE_A(0, 0, 0); STAGE_A(0, 1, 0); STAGE_B(0, 0, 0); STAGE_B(0, 1, 0);
  STAGE_A(1, 0, 1); STAGE_A(1, 1, 1); STAGE_B(1, 0, 1);
  WAIT_VM(6);
  S_BARRIER();
  READ_A(0, 0); READ_B(0, 0, bF0);

#pragma unroll 1
  for (int t = 0; t < NT; t += 2) {
    const bool s2 = (t + 2) < NT;
    const bool s3 = (t + 3) < NT;
    // ---- P1: MFMA A0xB0 (tile t); stage B1(t+1)->buf1; tail-read B1(t)
    S_BARRIER();
    STAGE_B(t + 1, 1, 1);
    MFMA8(0, 0, bF0);
    READ_B(0, 1, bF1);
    // ---- P2: MFMA A0xB1; stage A0(t+2)->buf0; tail-read A1(t)
    S_BARRIER();
    if (s2) STAGE_A(t + 2, 0, 0);
    MFMA8(0, 1, bF1);
    READ_A(0, 1);
    // ---- P3: MFMA A1xB1; stage B0(t+2)->buf0; drain tile-(t+1) DMA
    S_BARRIER();
    if (s2) STAGE_B(t + 2, 0, 0);
    MFMA8(1, 1, bF1);
    if (s2) { WAIT_VM(4); } else { WAIT_VM(0); }
    // ---- P4: MFMA A1xB0; stage A1(t+2)->buf0; tail-read A0,B0 (t+1, buf1)
    S_BARRIER();
    if (s2) STAGE_A(t + 2, 1, 0);
    MFMA8(1, 0, bF0);
    READ_A(1, 0); READ_B(1, 0, bF0);
    // ---- P5: MFMA A0xB0 (tile t+1); stage B1(t+2)->buf0; tail-read B1(t+1)
    S_BARRIER();
    if (s2) STAGE_B(t + 2, 1, 0);
    MFMA8(0, 0, bF0);
    READ_B(1, 1, bF1);
    // ---- P6: MFMA A0xB1; stage A0(t+3)->buf1; tail-read A1(t+1)
    S_BARRIER();
    if (s3) STAGE_A(t + 3, 0, 1);
    MFMA8(0, 1, bF1);
    READ_A(1, 1);
    // ---- P7: MFMA A1xB1; stage B0(t+3)->buf1; drain tile-(t+2) DMA
    S_BARRIER();
    if (s3) STAGE_B(t + 3, 0, 1);
    MFMA8(1, 1, bF1);
    if (s3) { WAIT_VM(4); } else { WAIT_VM(0); }
    // ---- P8: MFMA A1xB0; stage A1(t+3)->buf1; tail-read A0,B0 (t+2, buf0)
    S_BARRIER();
    if (s3) STAGE_A(t + 3, 1, 1);
    MFMA8(1, 0, bF0);
    if (s2) { READ_A(0, 0); READ_B(0, 0, bF0); }
  }

  // ---- epilogue: bias + store (fp32).  Tile (mh,mt,nh):
  // row = m0 + mh*128 + wm*64 + mt*32 + (reg&3) + 8*(reg>>2) + 4*(lane>>5)
  // col = n0 + nh*128 + wn*32 + (lane&31)
  float bs[2];
#pragma unroll
  for (int nh = 0; nh < 2; nh++)
    bs[nh] = bias[n0 + nh * 128 + wn * 32 + (lane & 31)];
  const int hrow = 4 * (lane >> 5);
#pragma unroll
  for (int i = 0; i < 4; i++) {  // i = mh*2 + mt
    int r0 = m0 + (i >> 1) * 128 + wm * 64 + (i & 1) * 32 + hrow;
#pragma unroll
    for (int nh = 0; nh < 2; nh++) {
      int cn = n0 + nh * 128 + wn * 32 + (lane & 31);
#pragma unroll
      for (int g = 0; g < 4; g++)
#pragma unroll
        for (int r = 0; r < 4; r++)
          C[(size_t)(r0 + 8 * g + r) * N_TOT + cn] = acc[i][nh][g * 4 + r] + bs[nh];
    }
  }
#undef STAGE_A
#undef STAGE_B
#undef READ_A
#undef READ_B
#undef MFMA8
}

// ---------------------------------------------------------------- launch
extern "C" void kernel_launch(void* const* d_in, const int* in_sizes, int n_in,
                              void* d_out, int out_size, void* d_ws, size_t ws_size,
                              hipStream_t stream) {
  const float* x        = (const float*)d_in[0];
  const int*   yidx     = (const int*)d_in[1];
  const float* codebook = (const float*)d_in[2];
  const float* W1       = (const float*)d_in[3];
  const float* b1       = (const float*)d_in[4];
  const float* W2       = (const float*)d_in[5];
  const float* b2       = (const float*)d_in[6];
  const float* scale    = (const float*)d_in[7];
  const float* shift    = (const float*)d_in[8];
  const float* bias     = (const float*)d_in[9];
  float* out = (float*)d_out;

  // Workspace layout (96 MB) -- R5-verified structure:
  //   [0,32MB)  What  (bf16)
  //   [32,96MB) xb    (bf16 x) -- first 4 MB double as fp32 decode table,
  //                               dead before convert_x runs (stream-ordered:
  //                               decode -> gather -> convert -> gemm).
  __hip_bfloat16* What = (__hip_bfloat16*)d_ws;                                     // 32 MB
  float* table = (float*)((char*)d_ws + (size_t)32 * 1024 * 1024);                  //  4 MB (aliased)
  __hip_bfloat16* xb   = (__hip_bfloat16*)((char*)d_ws + (size_t)32 * 1024 * 1024); // 64 MB

  decode_table_kernel<<<NCODES / 256, 256, 0, stream>>>(codebook, W1, b1, W2, b2,
                                                        table);
  gather_scale_kernel<<<NB / 256, 256, 0, stream>>>(yidx, table, scale, shift, What);
  convert_x_kernel<<<(M_TOT * (size_t)K_TOT) / (256 * 8), 256, 0, stream>>>(x, xb);
  gemm_32_kernel<<<512, 512, 0, stream>>>(xb, What, bias, out);
}